// Round 1
// baseline (600.857 us; speedup 1.0000x reference)
//
#include <hip/hip_runtime.h>
#include <hip/hip_bf16.h>

// Transducer joint: logits[b,t,u,:] = tanh(enc_out[b,t,:] + pred_out[b,u,:]) @ W_out + b_out
// B=4 T=256 U=64 D=512 J=1024 V=1024.
// Strategy: bf16 MFMA for all GEMMs; the dominant (65536x1024x1024) GEMM fuses the
// tanh(enc+pred) A-tile construction into LDS staging (no 134MB joint materialization).

typedef __bf16 bf16x8 __attribute__((ext_vector_type(8)));
typedef float f32x4 __attribute__((ext_vector_type(4)));
typedef unsigned int u32x4 __attribute__((ext_vector_type(4)));
using bf16_t = __hip_bfloat16;

#define B_ 4
#define T_ 256
#define U_ 64
#define DE 512
#define JD 1024
#define VV 1024

// async 16B/lane global->LDS. LDS dest is wave-uniform base + lane*16 (m104/m108):
// our layouts are contiguous in lane order.
__device__ __forceinline__ void gl2lds16(const void* g, void* l) {
  __builtin_amdgcn_global_load_lds(
      (__attribute__((address_space(1))) void*)(g),
      (__attribute__((address_space(3))) void*)(l), 16, 0, 0);
}

__device__ __forceinline__ float fast_tanh(float x) {
  float xx = fminf(fmaxf(x, -30.f), 30.f);       // guard overflow; tanh saturated anyway
  float e = __expf(2.f * xx);                    // v_exp_f32 based
  return 1.f - 2.f * __builtin_amdgcn_rcpf(e + 1.f);
}

// ---------------- fp32 -> bf16 elementwise (4 elems/thread) ----------------
__global__ void cvt_bf16_k(const float* __restrict__ src, bf16_t* __restrict__ dst, int n) {
  int i = (blockIdx.x * blockDim.x + threadIdx.x) * 4;
  if (i >= n) return;
  f32x4 v = *(const f32x4*)(src + i);
  bf16_t o[4];
#pragma unroll
  for (int z = 0; z < 4; ++z) o[z] = __float2bfloat16(v[z]);
  *(unsigned long long*)(dst + i) = *(unsigned long long*)o;
}

// ------------- fp32 [K][N] -> bf16 [N][K] tiled transpose ------------------
__global__ void transpose_cvt_k(const float* __restrict__ src, bf16_t* __restrict__ dst,
                                int K, int N) {
  __shared__ float tile[32][33];
  int nt = blockIdx.x * 32, kt = blockIdx.y * 32;
  int tx = threadIdx.x, ty = threadIdx.y;  // block (32,8)
#pragma unroll
  for (int i = 0; i < 4; ++i)
    tile[ty + i * 8][tx] = src[(size_t)(kt + ty + i * 8) * N + nt + tx];
  __syncthreads();
#pragma unroll
  for (int i = 0; i < 4; ++i)
    dst[(size_t)(nt + ty + i * 8) * K + kt + tx] = __float2bfloat16(tile[tx][ty + i * 8]);
}

// ------------- bf16 GEMM: C[M][N] = A[M][K] * Bt[N][K]^T + bias[N] ---------
// m97-style: 128x128 tile, BK=32, 256 threads = 4 waves in 2x2.
__global__ __launch_bounds__(256) void proj_gemm_k(
    const bf16_t* __restrict__ A, const bf16_t* __restrict__ Bt,
    const float* __restrict__ bias, float* __restrict__ C, int M, int N, int K) {
  __shared__ bf16_t sA[128 * 32];
  __shared__ bf16_t sB[128 * 32];
  const int tid = threadIdx.x;
  const int wave = tid >> 6, lane = tid & 63;
  const int wm = wave >> 1, wn = wave & 1;
  const int m0 = blockIdx.y * 128, n0 = blockIdx.x * 128;

  f32x4 acc[4][4] = {};

  for (int k0 = 0; k0 < K; k0 += 32) {
    __syncthreads();
#pragma unroll
    for (int r = 0; r < 2; ++r) {
      const int base = (wave + 4 * r) * 1024;      // byte offset into 8KB tile
      const int row  = (base >> 6) + (lane >> 2);  // 64B per row
      const int kel  = (lane & 3) * 8;
      gl2lds16(A  + (size_t)(m0 + row) * K + k0 + kel, (char*)sA + base);
      gl2lds16(Bt + (size_t)(n0 + row) * K + k0 + kel, (char*)sB + base);
    }
    __syncthreads();
    bf16x8 af[4], bfr[4];
    const int kq = (lane >> 4) * 8;
#pragma unroll
    for (int i = 0; i < 4; ++i) {
      af[i]  = *(const bf16x8*)(const void*)(sA + (wm * 64 + i * 16 + (lane & 15)) * 32 + kq);
      bfr[i] = *(const bf16x8*)(const void*)(sB + (wn * 64 + i * 16 + (lane & 15)) * 32 + kq);
    }
#pragma unroll
    for (int i = 0; i < 4; ++i)
#pragma unroll
      for (int j = 0; j < 4; ++j)
        acc[i][j] = __builtin_amdgcn_mfma_f32_16x16x32_bf16(af[i], bfr[j], acc[i][j], 0, 0, 0);
  }

  float bv[4];
#pragma unroll
  for (int j = 0; j < 4; ++j) bv[j] = bias[n0 + wn * 64 + j * 16 + (lane & 15)];
#pragma unroll
  for (int i = 0; i < 4; ++i) {
    const int row = m0 + wm * 64 + i * 16 + ((lane >> 4) << 2);
#pragma unroll
    for (int j = 0; j < 4; ++j) {
      const int col = n0 + wn * 64 + j * 16 + (lane & 15);
#pragma unroll
      for (int rr = 0; rr < 4; ++rr)
        C[(size_t)(row + rr) * N + col] = acc[i][j][rr] + bv[j];
    }
  }
}

// ------------- fused joint GEMM ------------------------------------------
// out[m][v] = tanh(enc_out[m>>6][k] + pred_out[(m>>14)*64+(m&63)][k]) @ Wt[v][k] + b_out[v]
__global__ __launch_bounds__(256) void joint_gemm_k(
    const float* __restrict__ enc_out,   // [B*T][JD]
    const float* __restrict__ pred_out,  // [B*U][JD]
    const bf16_t* __restrict__ Wt,       // [VV][JD]
    const float* __restrict__ b_out,     // [VV]
    float* __restrict__ out) {           // [B*T*U][VV]
  __shared__ bf16_t sA[128 * 32];
  __shared__ bf16_t sB[128 * 32];
  const int tid = threadIdx.x;
  const int wave = tid >> 6, lane = tid & 63;
  const int wm = wave >> 1, wn = wave & 1;
  const int m0 = blockIdx.y * 128, n0 = blockIdx.x * 128;

  // A-tile construction assignment: thread -> (row, 16-col half)
  const int ar  = tid >> 1;
  const int ac0 = (tid & 1) * 16;
  const int m = m0 + ar;
  const int enc_row  = m >> 6;                       // b*T + t
  const int pred_row = ((m >> 14) << 6) | (m & 63);  // b*U + u
  const float* pe_base = enc_out  + (size_t)enc_row  * JD + ac0;
  const float* pp_base = pred_out + (size_t)pred_row * JD + ac0;

  f32x4 acc[4][4] = {};

  for (int k0 = 0; k0 < JD; k0 += 32) {
    __syncthreads();
    // stage B tile (Wt rows n0..n0+127, k0..k0+31) via async 16B loads
#pragma unroll
    for (int r = 0; r < 2; ++r) {
      const int base = (wave + 4 * r) * 1024;
      const int row  = (base >> 6) + (lane >> 2);
      const int kel  = (lane & 3) * 8;
      gl2lds16(Wt + (size_t)(n0 + row) * JD + k0 + kel, (char*)sB + base);
    }
    // build A tile: tanh(enc+pred) -> bf16 -> LDS (16 elems/thread)
    bf16_t vals[16];
    const f32x4* pe = (const f32x4*)(pe_base + k0);
    const f32x4* pp = (const f32x4*)(pp_base + k0);
#pragma unroll
    for (int q = 0; q < 4; ++q) {
      f32x4 e = pe[q], p = pp[q];
#pragma unroll
      for (int z = 0; z < 4; ++z)
        vals[q * 4 + z] = __float2bfloat16(fast_tanh(e[z] + p[z]));
    }
    u32x4* dstp = (u32x4*)(void*)((char*)sA + ar * 64 + ac0 * 2);
    dstp[0] = ((const u32x4*)(const void*)vals)[0];
    dstp[1] = ((const u32x4*)(const void*)vals)[1];
    __syncthreads();

    bf16x8 af[4], bfr[4];
    const int kq = (lane >> 4) * 8;
#pragma unroll
    for (int i = 0; i < 4; ++i) {
      af[i]  = *(const bf16x8*)(const void*)(sA + (wm * 64 + i * 16 + (lane & 15)) * 32 + kq);
      bfr[i] = *(const bf16x8*)(const void*)(sB + (wn * 64 + i * 16 + (lane & 15)) * 32 + kq);
    }
#pragma unroll
    for (int i = 0; i < 4; ++i)
#pragma unroll
      for (int j = 0; j < 4; ++j)
        acc[i][j] = __builtin_amdgcn_mfma_f32_16x16x32_bf16(af[i], bfr[j], acc[i][j], 0, 0, 0);
  }

  float bv[4];
#pragma unroll
  for (int j = 0; j < 4; ++j) bv[j] = b_out[n0 + wn * 64 + j * 16 + (lane & 15)];
#pragma unroll
  for (int i = 0; i < 4; ++i) {
    const int row = m0 + wm * 64 + i * 16 + ((lane >> 4) << 2);
#pragma unroll
    for (int j = 0; j < 4; ++j) {
      const int col = n0 + wn * 64 + j * 16 + (lane & 15);
#pragma unroll
      for (int rr = 0; rr < 4; ++rr)
        out[(size_t)(row + rr) * VV + col] = acc[i][j][rr] + bv[j];
    }
  }
}

extern "C" void kernel_launch(void* const* d_in, const int* in_sizes, int n_in,
                              void* d_out, int out_size, void* d_ws, size_t ws_size,
                              hipStream_t stream) {
  const float* enc    = (const float*)d_in[0];  // [4,256,512]
  const float* pred   = (const float*)d_in[1];  // [4,64,512]
  const float* W_enc  = (const float*)d_in[2];  // [512,1024]
  const float* b_enc  = (const float*)d_in[3];  // [1024]
  const float* W_pred = (const float*)d_in[4];  // [512,1024]
  const float* b_pred = (const float*)d_in[5];  // [1024]
  const float* W_out  = (const float*)d_in[6];  // [1024,1024]
  const float* b_out  = (const float*)d_in[7];  // [1024]
  float* out = (float*)d_out;                   // [4,256,64,1024]

  char* ws = (char*)d_ws;  // layout (10.75 MB total)
  bf16_t* encb   = (bf16_t*)(ws + 0x000000);  // 1 MB   [1024][512]
  bf16_t* predb  = (bf16_t*)(ws + 0x100000);  // 256 KB [256][512]
  bf16_t* WtE    = (bf16_t*)(ws + 0x140000);  // 1 MB   [1024][512]
  bf16_t* WtP    = (bf16_t*)(ws + 0x240000);  // 1 MB   [1024][512]
  bf16_t* WtO    = (bf16_t*)(ws + 0x340000);  // 2 MB   [1024][1024]
  float*  enc_o  = (float*) (ws + 0x540000);  // 4 MB   [1024][1024]
  float*  pred_o = (float*) (ws + 0x940000);  // 1 MB   [256][1024]

  // conversions
  cvt_bf16_k<<<(B_*T_*DE) / 1024, 256, 0, stream>>>(enc, encb, B_*T_*DE);
  cvt_bf16_k<<<(B_*U_*DE) / 1024, 256, 0, stream>>>(pred, predb, B_*U_*DE);
  transpose_cvt_k<<<dim3(JD/32, DE/32), dim3(32, 8), 0, stream>>>(W_enc, WtE, DE, JD);
  transpose_cvt_k<<<dim3(JD/32, DE/32), dim3(32, 8), 0, stream>>>(W_pred, WtP, DE, JD);
  transpose_cvt_k<<<dim3(VV/32, JD/32), dim3(32, 8), 0, stream>>>(W_out, WtO, JD, VV);

  // projections (bias folded here; joint adds them via enc_o + pred_o)
  proj_gemm_k<<<dim3(JD/128, (B_*T_)/128), 256, 0, stream>>>(encb, WtE, b_enc, enc_o, B_*T_, JD, DE);
  proj_gemm_k<<<dim3(JD/128, (B_*U_)/128), 256, 0, stream>>>(predb, WtP, b_pred, pred_o, B_*U_, JD, DE);

  // fused tanh + vocab GEMM
  joint_gemm_k<<<dim3(VV/128, (B_*T_*U_)/128), 256, 0, stream>>>(enc_o, pred_o, WtO, b_out, out);
}

// Round 2
// 520.374 us; speedup vs baseline: 1.1547x; 1.1547x over previous
//
#include <hip/hip_runtime.h>
#include <hip/hip_bf16.h>

// Transducer joint: logits[b,t,u,:] = tanh(enc_out[b,t,:] + pred_out[b,u,:]) @ W_out + b_out
// B=4 T=256 U=64 D=512 J=1024 V=1024.
// R2: materialize tanh(joint) once as bf16 (134 MB ws) -> pure m97-style bf16 GEMM.
// (R1 fused version recomputed tanh x8 and was VALU-bound: MfmaUtil 16%, VALUBusy 64%.)
// Fallback to the R1 fused kernel if ws_size is too small.

typedef __bf16 bf16x8 __attribute__((ext_vector_type(8)));
typedef float f32x4 __attribute__((ext_vector_type(4)));
typedef unsigned int u32x4 __attribute__((ext_vector_type(4)));
using bf16_t = __hip_bfloat16;

#define B_ 4
#define T_ 256
#define U_ 64
#define DE 512
#define JD 1024
#define VV 1024

// async 16B/lane global->LDS. LDS dest is wave-uniform base + lane*16 (m104/m108):
// our layouts are contiguous in lane order.
__device__ __forceinline__ void gl2lds16(const void* g, void* l) {
  __builtin_amdgcn_global_load_lds(
      (__attribute__((address_space(1))) void*)(g),
      (__attribute__((address_space(3))) void*)(l), 16, 0, 0);
}

__device__ __forceinline__ float fast_tanh(float x) {
  float xx = fminf(fmaxf(x, -30.f), 30.f);       // guard overflow; tanh saturated anyway
  float e = __expf(2.f * xx);                    // v_exp_f32 based
  return 1.f - 2.f * __builtin_amdgcn_rcpf(e + 1.f);
}

// ---------------- fp32 -> bf16 elementwise (4 elems/thread) ----------------
__global__ void cvt_bf16_k(const float* __restrict__ src, bf16_t* __restrict__ dst, int n) {
  int i = (blockIdx.x * blockDim.x + threadIdx.x) * 4;
  if (i >= n) return;
  f32x4 v = *(const f32x4*)(src + i);
  bf16_t o[4];
#pragma unroll
  for (int z = 0; z < 4; ++z) o[z] = __float2bfloat16(v[z]);
  *(unsigned long long*)(dst + i) = *(unsigned long long*)o;
}

// ------------- fp32 [K][N] -> bf16 [N][K] tiled transpose ------------------
__global__ void transpose_cvt_k(const float* __restrict__ src, bf16_t* __restrict__ dst,
                                int K, int N) {
  __shared__ float tile[32][33];
  int nt = blockIdx.x * 32, kt = blockIdx.y * 32;
  int tx = threadIdx.x, ty = threadIdx.y;  // block (32,8)
#pragma unroll
  for (int i = 0; i < 4; ++i)
    tile[ty + i * 8][tx] = src[(size_t)(kt + ty + i * 8) * N + nt + tx];
  __syncthreads();
#pragma unroll
  for (int i = 0; i < 4; ++i)
    dst[(size_t)(nt + ty + i * 8) * K + kt + tx] = __float2bfloat16(tile[tx][ty + i * 8]);
}

// ------------- tanh materialize: joint[m][j] = tanh(enc_o + pred_o), bf16 ---
// m = (b*T + t)*U + u ; enc row = m>>6 ; pred row = (m>>14)<<6 | (m&63)
__global__ __launch_bounds__(256) void tanh_mat_k(
    const float* __restrict__ enc_o,   // [B*T][JD]
    const float* __restrict__ pred_o,  // [B*U][JD]
    bf16_t* __restrict__ joint) {      // [B*T*U][JD]
  size_t i = ((size_t)blockIdx.x * 256 + threadIdx.x) * 8;
  const int m = (int)(i >> 10);
  const int j = (int)(i & 1023);
  const int enc_row  = m >> 6;
  const int pred_row = ((m >> 14) << 6) | (m & 63);
  const f32x4* pe = (const f32x4*)(enc_o  + (size_t)enc_row  * JD + j);
  const f32x4* pp = (const f32x4*)(pred_o + (size_t)pred_row * JD + j);
  bf16_t vals[8];
#pragma unroll
  for (int q = 0; q < 2; ++q) {
    f32x4 e = pe[q], p = pp[q];
#pragma unroll
    for (int z = 0; z < 4; ++z)
      vals[q * 4 + z] = __float2bfloat16(fast_tanh(e[z] + p[z]));
  }
  *(u32x4*)(void*)(joint + i) = *(const u32x4*)(const void*)vals;
}

// ------------- bf16 GEMM: C[M][N] = A[M][K] * Bt[N][K]^T + bias[N] ---------
// m97-style: 128x128 tile, BK=32, 256 threads = 4 waves in 2x2.
__global__ __launch_bounds__(256) void proj_gemm_k(
    const bf16_t* __restrict__ A, const bf16_t* __restrict__ Bt,
    const float* __restrict__ bias, float* __restrict__ C, int M, int N, int K) {
  __shared__ bf16_t sA[128 * 32];
  __shared__ bf16_t sB[128 * 32];
  const int tid = threadIdx.x;
  const int wave = tid >> 6, lane = tid & 63;
  const int wm = wave >> 1, wn = wave & 1;
  const int m0 = blockIdx.y * 128, n0 = blockIdx.x * 128;

  f32x4 acc[4][4] = {};

  for (int k0 = 0; k0 < K; k0 += 32) {
    __syncthreads();
#pragma unroll
    for (int r = 0; r < 2; ++r) {
      const int base = (wave + 4 * r) * 1024;      // byte offset into 8KB tile
      const int row  = (base >> 6) + (lane >> 2);  // 64B per row
      const int kel  = (lane & 3) * 8;
      gl2lds16(A  + (size_t)(m0 + row) * K + k0 + kel, (char*)sA + base);
      gl2lds16(Bt + (size_t)(n0 + row) * K + k0 + kel, (char*)sB + base);
    }
    __syncthreads();
    bf16x8 af[4], bfr[4];
    const int kq = (lane >> 4) * 8;
#pragma unroll
    for (int i = 0; i < 4; ++i) {
      af[i]  = *(const bf16x8*)(const void*)(sA + (wm * 64 + i * 16 + (lane & 15)) * 32 + kq);
      bfr[i] = *(const bf16x8*)(const void*)(sB + (wn * 64 + i * 16 + (lane & 15)) * 32 + kq);
    }
#pragma unroll
    for (int i = 0; i < 4; ++i)
#pragma unroll
      for (int j = 0; j < 4; ++j)
        acc[i][j] = __builtin_amdgcn_mfma_f32_16x16x32_bf16(af[i], bfr[j], acc[i][j], 0, 0, 0);
  }

  float bv[4];
#pragma unroll
  for (int j = 0; j < 4; ++j) bv[j] = bias[n0 + wn * 64 + j * 16 + (lane & 15)];
#pragma unroll
  for (int i = 0; i < 4; ++i) {
    const int row = m0 + wm * 64 + i * 16 + ((lane >> 4) << 2);
#pragma unroll
    for (int j = 0; j < 4; ++j) {
      const int col = n0 + wn * 64 + j * 16 + (lane & 15);
#pragma unroll
      for (int rr = 0; rr < 4; ++rr)
        C[(size_t)(row + rr) * N + col] = acc[i][j][rr] + bv[j];
    }
  }
}

// ------------- R1 fallback: fused joint GEMM (used only if ws too small) ---
__global__ __launch_bounds__(256) void joint_gemm_k(
    const float* __restrict__ enc_out,   // [B*T][JD]
    const float* __restrict__ pred_out,  // [B*U][JD]
    const bf16_t* __restrict__ Wt,       // [VV][JD]
    const float* __restrict__ b_out,     // [VV]
    float* __restrict__ out) {           // [B*T*U][VV]
  __shared__ bf16_t sA[128 * 32];
  __shared__ bf16_t sB[128 * 32];
  const int tid = threadIdx.x;
  const int wave = tid >> 6, lane = tid & 63;
  const int wm = wave >> 1, wn = wave & 1;
  const int m0 = blockIdx.y * 128, n0 = blockIdx.x * 128;

  const int ar  = tid >> 1;
  const int ac0 = (tid & 1) * 16;
  const int m = m0 + ar;
  const int enc_row  = m >> 6;
  const int pred_row = ((m >> 14) << 6) | (m & 63);
  const float* pe_base = enc_out  + (size_t)enc_row  * JD + ac0;
  const float* pp_base = pred_out + (size_t)pred_row * JD + ac0;

  f32x4 acc[4][4] = {};

  for (int k0 = 0; k0 < JD; k0 += 32) {
    __syncthreads();
#pragma unroll
    for (int r = 0; r < 2; ++r) {
      const int base = (wave + 4 * r) * 1024;
      const int row  = (base >> 6) + (lane >> 2);
      const int kel  = (lane & 3) * 8;
      gl2lds16(Wt + (size_t)(n0 + row) * JD + k0 + kel, (char*)sB + base);
    }
    bf16_t vals[16];
    const f32x4* pe = (const f32x4*)(pe_base + k0);
    const f32x4* pp = (const f32x4*)(pp_base + k0);
#pragma unroll
    for (int q = 0; q < 4; ++q) {
      f32x4 e = pe[q], p = pp[q];
#pragma unroll
      for (int z = 0; z < 4; ++z)
        vals[q * 4 + z] = __float2bfloat16(fast_tanh(e[z] + p[z]));
    }
    u32x4* dstp = (u32x4*)(void*)((char*)sA + ar * 64 + ac0 * 2);
    dstp[0] = ((const u32x4*)(const void*)vals)[0];
    dstp[1] = ((const u32x4*)(const void*)vals)[1];
    __syncthreads();

    bf16x8 af[4], bfr[4];
    const int kq = (lane >> 4) * 8;
#pragma unroll
    for (int i = 0; i < 4; ++i) {
      af[i]  = *(const bf16x8*)(const void*)(sA + (wm * 64 + i * 16 + (lane & 15)) * 32 + kq);
      bfr[i] = *(const bf16x8*)(const void*)(sB + (wn * 64 + i * 16 + (lane & 15)) * 32 + kq);
    }
#pragma unroll
    for (int i = 0; i < 4; ++i)
#pragma unroll
      for (int j = 0; j < 4; ++j)
        acc[i][j] = __builtin_amdgcn_mfma_f32_16x16x32_bf16(af[i], bfr[j], acc[i][j], 0, 0, 0);
  }

  float bv[4];
#pragma unroll
  for (int j = 0; j < 4; ++j) bv[j] = b_out[n0 + wn * 64 + j * 16 + (lane & 15)];
#pragma unroll
  for (int i = 0; i < 4; ++i) {
    const int row = m0 + wm * 64 + i * 16 + ((lane >> 4) << 2);
#pragma unroll
    for (int j = 0; j < 4; ++j) {
      const int col = n0 + wn * 64 + j * 16 + (lane & 15);
#pragma unroll
      for (int rr = 0; rr < 4; ++rr)
        out[(size_t)(row + rr) * VV + col] = acc[i][j][rr] + bv[j];
    }
  }
}

extern "C" void kernel_launch(void* const* d_in, const int* in_sizes, int n_in,
                              void* d_out, int out_size, void* d_ws, size_t ws_size,
                              hipStream_t stream) {
  const float* enc    = (const float*)d_in[0];  // [4,256,512]
  const float* pred   = (const float*)d_in[1];  // [4,64,512]
  const float* W_enc  = (const float*)d_in[2];  // [512,1024]
  const float* b_enc  = (const float*)d_in[3];  // [1024]
  const float* W_pred = (const float*)d_in[4];  // [512,1024]
  const float* b_pred = (const float*)d_in[5];  // [1024]
  const float* W_out  = (const float*)d_in[6];  // [1024,1024]
  const float* b_out  = (const float*)d_in[7];  // [1024]
  float* out = (float*)d_out;                   // [4,256,64,1024]

  char* ws = (char*)d_ws;
  bf16_t* encb   = (bf16_t*)(ws + 0x000000);  // 1 MB   [1024][512]
  bf16_t* predb  = (bf16_t*)(ws + 0x100000);  // 256 KB [256][512]
  bf16_t* WtE    = (bf16_t*)(ws + 0x140000);  // 1 MB   [1024][512]
  bf16_t* WtP    = (bf16_t*)(ws + 0x240000);  // 1 MB   [1024][512]
  bf16_t* WtO    = (bf16_t*)(ws + 0x340000);  // 2 MB   [1024][1024]
  float*  enc_o  = (float*) (ws + 0x540000);  // 4 MB   [1024][1024]
  float*  pred_o = (float*) (ws + 0x940000);  // 1 MB   [256][1024]
  bf16_t* joint  = (bf16_t*)(ws + 0xA40000);  // 128 MB [65536][1024]
  const size_t WS_NEEDED = 0xA40000 + (size_t)(B_*T_*U_) * JD * sizeof(bf16_t);

  // conversions
  cvt_bf16_k<<<(B_*T_*DE) / 1024, 256, 0, stream>>>(enc, encb, B_*T_*DE);
  cvt_bf16_k<<<(B_*U_*DE) / 1024, 256, 0, stream>>>(pred, predb, B_*U_*DE);
  transpose_cvt_k<<<dim3(JD/32, DE/32), dim3(32, 8), 0, stream>>>(W_enc, WtE, DE, JD);
  transpose_cvt_k<<<dim3(JD/32, DE/32), dim3(32, 8), 0, stream>>>(W_pred, WtP, DE, JD);
  transpose_cvt_k<<<dim3(VV/32, JD/32), dim3(32, 8), 0, stream>>>(W_out, WtO, JD, VV);

  // projections (bias folded here; joint adds them via enc_o + pred_o)
  proj_gemm_k<<<dim3(JD/128, (B_*T_)/128), 256, 0, stream>>>(encb, WtE, b_enc, enc_o, B_*T_, JD, DE);
  proj_gemm_k<<<dim3(JD/128, (B_*U_)/128), 256, 0, stream>>>(predb, WtP, b_pred, pred_o, B_*U_, JD, DE);

  if (ws_size >= WS_NEEDED) {
    // materialize tanh(joint) once, then pure bf16 GEMM (VALU off the critical path)
    tanh_mat_k<<<(B_*T_*U_) * JD / (8 * 256), 256, 0, stream>>>(enc_o, pred_o, joint);
    proj_gemm_k<<<dim3(VV/128, (B_*T_*U_)/128), 256, 0, stream>>>(joint, WtO, b_out, out,
                                                                  B_*T_*U_, VV, JD);
  } else {
    // fallback: fused tanh + vocab GEMM (R1 path)
    joint_gemm_k<<<dim3(VV/128, (B_*T_*U_)/128), 256, 0, stream>>>(enc_o, pred_o, WtO, b_out, out);
  }
}